// Round 7
// baseline (384.254 us; speedup 1.0000x reference)
//
#include <hip/hip_runtime.h>
#include <math.h>

#define LEPS 1e-5f
static constexpr int NPOS = 65536;   // B*H*W = 16*64*64

typedef __attribute__((ext_vector_type(8))) short short8;
typedef __attribute__((ext_vector_type(4))) float floatx4;

__device__ __forceinline__ ushort f2bf(float f) {
    unsigned int u = __float_as_uint(f);
    u += 0x7FFF + ((u >> 16) & 1);          // RNE
    return (ushort)(u >> 16);
}
__device__ __forceinline__ float bfu(ushort h) {
    return __uint_as_float((unsigned int)h << 16);
}
__device__ __forceinline__ float bfl(unsigned int u) {
    return __uint_as_float(u << 16);
}
__device__ __forceinline__ float bfh(unsigned int u) {
    return __uint_as_float(u & 0xffff0000u);
}

// direct global -> LDS DMA, 16B per lane.  LDS dest = wave-uniform base + lane*16.
typedef __attribute__((address_space(1))) const unsigned int gu32_t;
typedef __attribute__((address_space(3))) unsigned int lu32_t;
__device__ __forceinline__ void gld16(const ushort* g, ushort* l) {
    __builtin_amdgcn_global_load_lds((gu32_t*)g, (lu32_t*)l, 16, 0, 0);
}

// ---------------------------------------------------------------------------
// Weight fp32 -> bf16, 6 segments (grid.y = segment)
// ---------------------------------------------------------------------------
struct WcvtArgs { const float* src[6]; ushort* dst[6]; int n[6]; };
__global__ __launch_bounds__(256)
void wcvt_k(WcvtArgs a)
{
    const int seg = blockIdx.y;
    const float* s = a.src[seg];
    ushort* d = a.dst[seg];
    const int n = a.n[seg];
    for (int i = blockIdx.x * 256 + threadIdx.x; i < n; i += gridDim.x * 256)
        d[i] = f2bf(s[i]);
}

// BN fold for both BNs in one launch (grid.x = which)
__global__ __launch_bounds__(256)
void bnprep_k(const float* g1, const float* b1, const float* m1, const float* v1,
              const float* g2, const float* b2, const float* m2, const float* v2,
              float* s1, float* h1, float* s2, float* h2)
{
    const int i = threadIdx.x;
    if (blockIdx.x == 0) {
        const float s = g1[i] * rsqrtf(v1[i] + LEPS);
        s1[i] = s; h1[i] = b1[i] - m1[i] * s;
    } else {
        const float s = g2[i] * rsqrtf(v2[i] + LEPS);
        s2[i] = s; h2[i] = b2[i] - m2[i] * s;
    }
}

// ---------------------------------------------------------------------------
// MFMA bf16 GEMM, 64x128 tile, BK=64, double-buffered with counted vmcnt
// (2-phase).  LDS 48 KB -> 3 blocks/CU.  128-B rows, zero-conflict XOR
// chunk-swizzle (pre-swizzled global source / swizzled write + swizzled
// fragment ds_read col).  Grid: (p-tiles, o-tiles) p-major.
// AMODE 0: A0 bf16, stride ARS.   AMODE 2: concat(A0 256-stride, A1 128).
// AMODE 3: avg(A0,A1) stride 128, reg-staged issue-early/write-late.
// AMODE 4: A = x NCHW fp32, fused transpose+cvt staging (replaces tr_k):
//          thread reads 2 adjacent ch rows x 8 pos (4 float4), packs
//          (ch,ch+1) bf16 pairs, 8 ds_write_b32 into swizzled [pos][ch].
// EPI 0:+bias->bf16  1:BN+SiLU->bf16 (cv1)  2:BN+SiLU->fp32 NCHW (cv2)
// EPI 4: res(y2) + (v+bias)*gamma -> bf16 (proj)
// LN=1: additionally LayerNorm each 128-ch row of this tile -> lnout
// ---------------------------------------------------------------------------
template<int KDIM, int ARS, int AMODE, int EPI, int LN>
__global__ __launch_bounds__(256)
void gemm_k(const ushort* __restrict__ A0, const ushort* __restrict__ A1,
            const ushort* __restrict__ Wm, const float* __restrict__ bias,
            const float* __restrict__ q0, const float* __restrict__ q1,
            const ushort* __restrict__ resh,
            const float* __restrict__ lng, const float* __restrict__ lnb,
            ushort* __restrict__ lnout, void* __restrict__ outv, int ors)
{
    constexpr int NT = KDIM / 64;
    __shared__ __align__(16) ushort smem[24576];   // 48 KB
    const int t = threadIdx.x;
    const int p0 = blockIdx.x * 64;           // position tile (p-major adjacency)
    const int o0 = blockIdx.y * 128;          // output-channel tile
    const int lane = t & 63, wv = t >> 6;
    const int wn = wv * 32;                   // per-wave 64x32 output
    const int ln15 = lane & 15, quad = lane >> 4;
    // DMA lane mapping: 8 lanes/row, source chunk pre-swizzled (chunk^row&7)
    const int dl_row = lane >> 3;
    const int dl_sch = (lane & 7) ^ dl_row;
    // fragment col offsets per kc half (swizzled)
    const int c_off0 = ((quad) ^ (ln15 & 7)) * 8;
    const int c_off1 = ((4 + quad) ^ (ln15 & 7)) * 8;
    floatx4 acc[4][2] = {};

    // AMODE 3 reg-staging state (64 rows x 64 cols, 32 B/thread)
    const int a3row = t >> 2, a3q = t & 3;
    uint4 ra[2], rb4[2];

    // AMODE 4 state: thread covers ch pair (2*x_c, +1) x 8 pos (x_o*8..+8)
    const int x_c = t & 31, x_o = t >> 5;
    float4 xa0, xa1, xb0, xb1;

    auto stageA = [&](int k0, int bc) {            // AMODE 0/2: 2 instr/wave
#pragma unroll
        for (int i = 0; i < 2; i++) {
            const int r0 = wv * 16 + i * 8;
            const int row = r0 + dl_row;
            const ushort* src;
            if (AMODE == 2) {
                if (k0 < 256) src = A0 + (size_t)(p0 + row) * 256 + k0 + dl_sch * 8;
                else          src = A1 + (size_t)(p0 + row) * 128 + (k0 - 256) + dl_sch * 8;
            } else {
                src = A0 + (size_t)(p0 + row) * ARS + k0 + dl_sch * 8;
            }
            gld16(src, &smem[bc * 4096 + r0 * 64]);
        }
    };
    auto stageB = [&](int k0, int bc) {            // 4 instr/wave
#pragma unroll
        for (int i = 0; i < 4; i++) {
            const int r0 = wv * 32 + i * 8;
            gld16(Wm + (size_t)(o0 + r0 + dl_row) * KDIM + k0 + dl_sch * 8,
                  &smem[8192 + bc * 8192 + r0 * 64]);
        }
    };
    auto loadA3 = [&](int k0) {
        const ushort* s1 = A0 + (size_t)(p0 + a3row) * 128 + k0 + a3q * 16;
        const ushort* s2 = A1 + (size_t)(p0 + a3row) * 128 + k0 + a3q * 16;
#pragma unroll
        for (int i = 0; i < 2; i++) { ra[i] = ((const uint4*)s1)[i]; rb4[i] = ((const uint4*)s2)[i]; }
    };
    auto writeA3 = [&](int bc) {
#pragma unroll
        for (int i = 0; i < 2; i++) {
            const unsigned int* ap = (const unsigned int*)&ra[i];
            const unsigned int* bp = (const unsigned int*)&rb4[i];
            uint4 w; unsigned int* wp = (unsigned int*)&w;
#pragma unroll
            for (int j = 0; j < 4; j++)
                wp[j] = (unsigned int)f2bf(0.5f * (bfl(ap[j]) + bfl(bp[j])))
                      | ((unsigned int)f2bf(0.5f * (bfh(ap[j]) + bfh(bp[j]))) << 16);
            const int pch = (a3q * 2 + i) ^ (a3row & 7);
            *(uint4*)&smem[bc * 4096 + a3row * 64 + pch * 8] = w;
        }
    };
    // AMODE 4: x NCHW fp32 -> A tile (fused transpose + cvt)
    auto loadX = [&](int k0) {
        const float* X = (const float*)A0;
        const float* sp = X + (((size_t)(p0 >> 12) * 256 + k0 + 2 * x_c) << 12)
                            + (p0 & 4095) + x_o * 8;
        xa0 = *(const float4*)sp;
        xa1 = *(const float4*)(sp + 4);
        xb0 = *(const float4*)(sp + 4096);
        xb1 = *(const float4*)(sp + 4100);
    };
    auto writeX = [&](int bc) {
        const int c = 2 * x_c;
        const int c8 = c >> 3, cl = c & 7;
        const float* l0 = (const float*)&xa0;
        const float* l1 = (const float*)&xa1;
        const float* h0 = (const float*)&xb0;
        const float* h1 = (const float*)&xb1;
#pragma unroll
        for (int i = 0; i < 4; i++) {
            const int pos = x_o * 8 + i;
            unsigned int w = (unsigned int)f2bf(l0[i]) | ((unsigned int)f2bf(h0[i]) << 16);
            *(unsigned int*)&smem[bc * 4096 + pos * 64 + (c8 ^ (pos & 7)) * 8 + cl] = w;
        }
#pragma unroll
        for (int i = 0; i < 4; i++) {
            const int pos = x_o * 8 + 4 + i;
            unsigned int w = (unsigned int)f2bf(l1[i]) | ((unsigned int)f2bf(h1[i]) << 16);
            *(unsigned int*)&smem[bc * 4096 + pos * 64 + (c8 ^ (pos & 7)) * 8 + cl] = w;
        }
    };
    auto compute = [&](int bc) {
#pragma unroll
        for (int kh = 0; kh < 2; kh++) {
            const int co = kh ? c_off1 : c_off0;
            short8 a[4], b[2];
#pragma unroll
            for (int i = 0; i < 4; i++)
                a[i] = *(const short8*)&smem[bc * 4096 + (i * 16 + ln15) * 64 + co];
#pragma unroll
            for (int j = 0; j < 2; j++)
                b[j] = *(const short8*)&smem[8192 + bc * 8192 + (wn + j * 16 + ln15) * 64 + co];
#pragma unroll
            for (int i = 0; i < 4; i++)
#pragma unroll
                for (int j = 0; j < 2; j++)
                    acc[i][j] = __builtin_amdgcn_mfma_f32_16x16x32_bf16(
                        a[i], b[j], acc[i][j], 0, 0, 0);
        }
    };

    if (AMODE == 3 || AMODE == 4) {
        if (AMODE == 3) loadA3(0); else loadX(0);
        stageB(0, 0);
#pragma unroll
        for (int tt = 0; tt < NT; ++tt) {
            const int cur = tt & 1;
            if (AMODE == 3) writeA3(cur); else writeX(cur);   // waits own regs
            if (tt + 1 < NT) {
                if (AMODE == 3) loadA3((tt + 1) * 64); else loadX((tt + 1) * 64);
                stageB((tt + 1) * 64, cur ^ 1);
                asm volatile("s_waitcnt vmcnt(8) lgkmcnt(0)" ::: "memory");
            } else {
                asm volatile("s_waitcnt vmcnt(0) lgkmcnt(0)" ::: "memory");
            }
            __builtin_amdgcn_s_barrier();
            __builtin_amdgcn_sched_barrier(0);
            compute(cur);
            __builtin_amdgcn_sched_barrier(0);
            __builtin_amdgcn_s_barrier();
        }
    } else {
        stageA(0, 0); stageB(0, 0);
#pragma unroll
        for (int tt = 0; tt < NT; ++tt) {
            const int cur = tt & 1;
            if (tt + 1 < NT) {
                stageA((tt + 1) * 64, cur ^ 1);
                stageB((tt + 1) * 64, cur ^ 1);
                asm volatile("s_waitcnt vmcnt(6)" ::: "memory");
            } else {
                asm volatile("s_waitcnt vmcnt(0)" ::: "memory");
            }
            __builtin_amdgcn_s_barrier();
            __builtin_amdgcn_sched_barrier(0);
            compute(cur);
            __builtin_amdgcn_sched_barrier(0);
            __builtin_amdgcn_s_barrier();
        }
    }

    if (EPI == 2) {
        // BN+SiLU, coalesced NCHW fp32 store via LDS transpose (two 64-ch chunks)
        float* cb = (float*)smem;                       // [64][72] fp32 = 18.4 KB
        float* ob = (float*)outv + (((size_t)(p0 >> 12) * 256) << 12);
        const int hw0 = p0 & 4095;
#pragma unroll
        for (int chunk = 0; chunk < 2; chunk++) {
            __syncthreads();
            if ((wv >> 1) == chunk) {
#pragma unroll
                for (int i = 0; i < 4; i++)
#pragma unroll
                for (int j = 0; j < 2; j++) {
                    const int chl = (wv & 1) * 32 + j * 16 + ln15;
                    const int o = o0 + chunk * 64 + chl;
                    const float sc = q0[o], sh = q1[o];
#pragma unroll
                    for (int r = 0; r < 4; r++) {
                        const int pos = i * 16 + quad * 4 + r;
                        float v = acc[i][j][r] * sc + sh;
                        v = v / (1.f + __expf(-v));
                        cb[chl * 72 + pos] = v;
                    }
                }
            }
            __syncthreads();
#pragma unroll
            for (int it = 0; it < 4; it++) {
                const int flat = it * 256 + t;
                const int ch = flat >> 4, posq = (flat & 15) * 4;
                const int o = o0 + chunk * 64 + ch;
                float4 v4 = *(const float4*)&cb[ch * 72 + posq];
                *(float4*)&ob[((size_t)o << 12) + hw0 + posq] = v4;
            }
        }
        return;
    }

    // ---- EPI 0/1/4: epilogue through LDS tile (also feeds LN) ----
    const bool lnact = LN && (EPI != 1 || o0 == 128);
    ushort (*lt)[136] = (ushort (*)[136])smem;          // 64 x 136 = 17.4 KB
#pragma unroll
    for (int i = 0; i < 4; i++) {
#pragma unroll
        for (int r = 0; r < 4; r++) {
            const int lr = i * 16 + quad * 4 + r;       // 0..63
            const int p = p0 + lr;
#pragma unroll
            for (int j = 0; j < 2; j++) {
                const int ol = wn + j * 16 + ln15;
                const int o = o0 + ol;
                float v = acc[i][j][r];
                if (EPI == 0) {
                    v += bias[o];
                } else if (EPI == 1) {
                    v = v * q0[o] + q1[o];
                    v = v / (1.f + __expf(-v));
                } else if (EPI == 4) {
                    v = bfu(resh[(size_t)p * 256 + 128 + o]) + (v + bias[o]) * q0[o];
                }
                lt[lr][ol] = f2bf(v);
            }
        }
    }
    __syncthreads();
    // coalesced store: 64 rows x 256 B, 4 x uint4 per thread
    {
        ushort* o16 = (ushort*)outv;
#pragma unroll
        for (int it = 0; it < 4; it++) {
            const int flat = it * 256 + t;
            const int row = flat >> 4, ch = (flat & 15) * 8;
            *(uint4*)&o16[(size_t)(p0 + row) * (size_t)ors + o0 + ch] =
                *(const uint4*)&lt[row][ch];
        }
    }

    if (lnact && t < 128) {
        const int rrow = t >> 1, rhalf = t & 1;         // rrow 0..63
        const ushort* rp = &lt[rrow][rhalf * 64];
        float s = 0.f, s2 = 0.f;
#pragma unroll
        for (int i = 0; i < 8; i++) {
            const uint4 u = *(const uint4*)(rp + i * 8);
            const unsigned int ww[4] = {u.x, u.y, u.z, u.w};
#pragma unroll
            for (int j = 0; j < 4; j++) {
                const float a = bfl(ww[j]), c = bfh(ww[j]);
                s += a + c; s2 += a * a + c * c;
            }
        }
        s += __shfl_xor(s, 1); s2 += __shfl_xor(s2, 1);
        const float mu = s * (1.f / 128.f);
        const float rn = rsqrtf(s2 * (1.f / 128.f) - mu * mu + LEPS);
        ushort* op = lnout + (size_t)(p0 + rrow) * 128 + rhalf * 64;
#pragma unroll
        for (int i = 0; i < 8; i++) {
            const uint4 u = *(const uint4*)(rp + i * 8);
            const unsigned int ww[4] = {u.x, u.y, u.z, u.w};
            uint4 wout;
            unsigned int* wo = (unsigned int*)&wout;
#pragma unroll
            for (int j = 0; j < 4; j++) {
                const int ch = rhalf * 64 + i * 8 + j * 2;
                const float2 gg = *(const float2*)(lng + ch);
                const float2 bb = *(const float2*)(lnb + ch);
                const float a = (bfl(ww[j]) - mu) * rn * gg.x + bb.x;
                const float c = (bfh(ww[j]) - mu) * rn * gg.y + bb.y;
                wo[j] = (unsigned int)f2bf(a) | ((unsigned int)f2bf(c) << 16);
            }
            *(uint4*)(op + i * 8) = wout;
        }
    }
}

// ---------------------------------------------------------------------------
// Fused FFN: f += W2 @ gelu(W1 @ fn2 + b1) + b2.  64 positions/block.
// GEMM2 w2 tiles double-buffered (counted vmcnt); w2 tile0 prefetched across
// the H1 epilogue; f-RMW tile prefetched under GEMM2's last step.
// ---------------------------------------------------------------------------
__global__ __launch_bounds__(256)
void ffn_k(const ushort* __restrict__ fn2, const ushort* __restrict__ w1,
           const float* __restrict__ b1, const ushort* __restrict__ w2,
           const float* __restrict__ b2, ushort* __restrict__ f)
{
    __shared__ __align__(16) ushort smem[64 * 64 + 256 * 64 + 64 * 264]; // 74.8 KB
    ushort* Ax = smem;                                   // [64][64] swz
    ushort* Wt = smem + 64 * 64;                         // GEMM1 [256][64]; GEMM2 2x[128][64]
    ushort (*H1)[264] = (ushort (*)[264])(smem + 64 * 64 + 256 * 64);    // 64 x 264
    const int t = threadIdx.x;
    const int p0 = blockIdx.x * 64;
    const int lane = t & 63, wv = t >> 6;
    const int ln15 = lane & 15, quad = lane >> 4;
    const int dl_row = lane >> 3;
    const int dl_sch = (lane & 7) ^ dl_row;
    const int c_off0 = ((quad) ^ (ln15 & 7)) * 8;
    const int c_off1 = ((4 + quad) ^ (ln15 & 7)) * 8;

    // bias values hoisted to regs (keeps the epilogue vmem-free for counting)
    float bb1[4], bb2[2];
#pragma unroll
    for (int j = 0; j < 4; j++) bb1[j] = b1[wv * 64 + j * 16 + ln15];
#pragma unroll
    for (int j = 0; j < 2; j++) bb2[j] = b2[wv * 32 + j * 16 + ln15];

    // ---- GEMM1: h1[64][256] = gelu(fn2 @ w1^T + b1), wave wv -> ch [wv*64,+64)
    floatx4 acc1[4][4] = {};
    for (int k0 = 0; k0 < 128; k0 += 64) {
#pragma unroll
        for (int i = 0; i < 2; i++) {
            const int r0 = wv * 16 + i * 8;
            gld16(fn2 + (size_t)(p0 + r0 + dl_row) * 128 + k0 + dl_sch * 8, &Ax[r0 * 64]);
        }
#pragma unroll
        for (int i = 0; i < 8; i++) {
            const int r0 = wv * 64 + i * 8;
            gld16(w1 + (size_t)(r0 + dl_row) * 128 + k0 + dl_sch * 8, &Wt[r0 * 64]);
        }
        __syncthreads();
#pragma unroll
        for (int kh = 0; kh < 2; kh++) {
            const int co = kh ? c_off1 : c_off0;
            short8 a[4], b[4];
#pragma unroll
            for (int i = 0; i < 4; i++)
                a[i] = *(const short8*)&Ax[(i * 16 + ln15) * 64 + co];
#pragma unroll
            for (int j = 0; j < 4; j++)
                b[j] = *(const short8*)&Wt[(wv * 64 + j * 16 + ln15) * 64 + co];
#pragma unroll
            for (int i = 0; i < 4; i++)
#pragma unroll
                for (int j = 0; j < 4; j++)
                    acc1[i][j] = __builtin_amdgcn_mfma_f32_16x16x32_bf16(
                        a[i], b[j], acc1[i][j], 0, 0, 0);
        }
        __syncthreads();
    }
    // issue w2 tile0 DMA now (overlaps the H1 epilogue below)
#pragma unroll
    for (int i = 0; i < 4; i++) {
        const int r0 = wv * 32 + i * 8;
        gld16(w2 + (size_t)(r0 + dl_row) * 256 + dl_sch * 8, &Wt[r0 * 64]);
    }
    {
#pragma unroll
        for (int i = 0; i < 4; i++)
#pragma unroll
        for (int j = 0; j < 4; j++)
#pragma unroll
        for (int r = 0; r < 4; r++) {
            float v = acc1[i][j][r] + bb1[j];
            v = 0.5f * v * (1.f + erff(v * 0.70710678118654752f));
            H1[i * 16 + quad * 4 + r][wv * 64 + j * 16 + ln15] = f2bf(v);
        }
    }
    asm volatile("s_waitcnt lgkmcnt(0)" ::: "memory");   // H1 writes visible; w2 DMA flies
    __builtin_amdgcn_s_barrier();
    __builtin_amdgcn_sched_barrier(0);

    // ---- GEMM2: fo[64][128] = h1 @ w2^T, w2 tiles double-buffered ----
    floatx4 acc2[4][2] = {};
#pragma unroll
    for (int t4 = 0; t4 < 4; ++t4) {
        const int cur = t4 & 1;
        if (t4 + 1 < 4) {
#pragma unroll
            for (int i = 0; i < 4; i++) {
                const int r0 = wv * 32 + i * 8;
                gld16(w2 + (size_t)(r0 + dl_row) * 256 + (t4 + 1) * 64 + dl_sch * 8,
                      &Wt[(cur ^ 1) * 8192 + r0 * 64]);
            }
            asm volatile("s_waitcnt vmcnt(4)" ::: "memory");
        } else {
            // prefetch f tile for the RMW (lands in Ax+WtB0 region, both idle)
#pragma unroll
            for (int i = 0; i < 4; i++) {
                const int r0 = wv * 16 + i * 4;
                gld16(f + (size_t)(p0 + r0 + (lane >> 4)) * 128 + (lane & 15) * 8,
                      &smem[r0 * 128]);
            }
            asm volatile("s_waitcnt vmcnt(4)" ::: "memory");
        }
        __builtin_amdgcn_s_barrier();
        __builtin_amdgcn_sched_barrier(0);
#pragma unroll
        for (int kh = 0; kh < 2; kh++) {
            const int co = kh ? c_off1 : c_off0;
            short8 a[4], b[2];
#pragma unroll
            for (int i = 0; i < 4; i++)
                a[i] = *(const short8*)&H1[i * 16 + ln15][t4 * 64 + kh * 32 + quad * 8];
#pragma unroll
            for (int j = 0; j < 2; j++)
                b[j] = *(const short8*)&Wt[cur * 8192 + (wv * 32 + j * 16 + ln15) * 64 + co];
#pragma unroll
            for (int i = 0; i < 4; i++)
#pragma unroll
                for (int j = 0; j < 2; j++)
                    acc2[i][j] = __builtin_amdgcn_mfma_f32_16x16x32_bf16(
                        a[i], b[j], acc2[i][j], 0, 0, 0);
        }
        __builtin_amdgcn_sched_barrier(0);
        __builtin_amdgcn_s_barrier();
    }
    asm volatile("s_waitcnt vmcnt(0)" ::: "memory");     // all waves' f-DMA done
    __builtin_amdgcn_s_barrier();

    // ---- f RMW in LDS, then coalesced store back ----
    ushort* Ft = smem;                                   // [64][128] linear
    {
#pragma unroll
        for (int i = 0; i < 4; i++)
#pragma unroll
        for (int r = 0; r < 4; r++) {
            const int pos = i * 16 + quad * 4 + r;
#pragma unroll
            for (int j = 0; j < 2; j++) {
                const int ch = wv * 32 + j * 16 + ln15;
                const int idx = pos * 128 + ch;
                Ft[idx] = f2bf(bfu(Ft[idx]) + acc2[i][j][r] + bb2[j]);
            }
        }
    }
    __syncthreads();
#pragma unroll
    for (int it = 0; it < 4; it++) {
        const int flat = it * 256 + t;
        const int row = flat >> 4, ch = (flat & 15) * 8;
        *(uint4*)&f[(size_t)(p0 + row) * 128 + ch] = *(const uint4*)&Ft[row * 128 + ch];
    }
}

// ---------------------------------------------------------------------------
// MFMA axial decay attention, both directions in one launch (blockIdx.y).
// ---------------------------------------------------------------------------
__global__ __launch_bounds__(256)
void attn_k(const ushort* __restrict__ qkv, ushort* __restrict__ oh,
            ushort* __restrict__ ow)
{
    __shared__ ushort VtS[4][16 * 72];    // V^T [d][j], stride 72
    __shared__ ushort SbS[4][64 * 72];    // S   [i][j], stride 72
    __shared__ float dpow[128];           // dpow[k] = e^{dec*|k-63|}
    const int t = threadIdx.x, wv = t >> 6, lane = t & 63;
    const int ln15 = lane & 15, quad = lane >> 4;
    const int dirH = (blockIdx.y == 0);
    ushort* outb = dirH ? oh : ow;
    const int blk = blockIdx.x;               // (b*8+n)*16 + lg
    const int lg = blk & 15, n = (blk >> 4) & 7, b = blk >> 7;
    if (t < 128) {
        const float dec = logf(1.f - exp2f(-2.f - 0.5f * (float)n));
        int d = t - 63; if (d < 0) d = -d;
        dpow[t] = __expf(dec * (float)d);
    }
    const int fixed = lg * 4 + wv;
    const int stride = dirH ? 64 : 1;
    const size_t base = (size_t)b * 4096 + (dirH ? fixed : fixed * 64);
    const size_t cbase = base * 384 + n * 16;

    // ---- stage V^T into LDS (lane = position j) ----
    {
        const ushort* vp = qkv + cbase + (size_t)lane * stride * 384 + 256;
        const uint4 va = *(const uint4*)vp, vb = *(const uint4*)(vp + 8);
        ushort* vt = VtS[wv] + lane;
        const unsigned int w[8] = { va.x, va.y, va.z, va.w, vb.x, vb.y, vb.z, vb.w };
#pragma unroll
        for (int d = 0; d < 8; d++) {
            vt[(2 * d) * 72]     = (ushort)(w[d] & 0xffff);
            vt[(2 * d + 1) * 72] = (ushort)(w[d] >> 16);
        }
    }
    // ---- load Q/K fragments (16x16x32, K dim padded 16->32) ----
    short8 qa[4], kb[4];
    {
        const short8 z = {0, 0, 0, 0, 0, 0, 0, 0};
#pragma unroll
        for (int mt = 0; mt < 4; mt++) {
            const int i = mt * 16 + ln15;
            if (quad < 2) {
                const ushort* qp = qkv + cbase + (size_t)i * stride * 384 + quad * 8;
                qa[mt] = *(const short8*)qp;
                kb[mt] = *(const short8*)(qp + 128);
            } else { qa[mt] = z; kb[mt] = z; }
        }
    }
    __syncthreads();

    // ---- QK^T + decay -> Sb (bf16 row-major) ----
#pragma unroll
    for (int mt = 0; mt < 4; mt++) {
#pragma unroll
        for (int nt = 0; nt < 4; nt++) {
            floatx4 c = {0.f, 0.f, 0.f, 0.f};
            c = __builtin_amdgcn_mfma_f32_16x16x32_bf16(qa[mt], kb[nt], c, 0, 0, 0);
            const int i0 = mt * 16 + quad * 4;
            const int jl = nt * 16 + ln15;
            const float* lut = dpow + (i0 - jl + 63);
            ushort* sb = SbS[wv] + i0 * 72 + jl;
#pragma unroll
            for (int r = 0; r < 4; r++)
                sb[r * 72] = f2bf(c[r] * lut[r]);
        }
    }
    __syncthreads();

    // ---- O^T = V^T * S^T  (M=16 d, N=64 i, K=64 j) ----
    short8 av[2];
#pragma unroll
    for (int c = 0; c < 2; c++)
        av[c] = *(const short8*)&VtS[wv][ln15 * 72 + c * 32 + quad * 8];
    floatx4 o[4] = {};
#pragma unroll
    for (int nt4 = 0; nt4 < 4; nt4++) {
#pragma unroll
        for (int c = 0; c < 2; c++) {
            const short8 bs = *(const short8*)
                &SbS[wv][(nt4 * 16 + ln15) * 72 + c * 32 + quad * 8];
            o[nt4] = __builtin_amdgcn_mfma_f32_16x16x32_bf16(av[c], bs, o[nt4], 0, 0, 0);
        }
    }
#pragma unroll
    for (int nt4 = 0; nt4 < 4; nt4++) {
        const int i = nt4 * 16 + ln15;
        ushort* op = outb + (base + (size_t)i * stride) * 128 + n * 16 + quad * 4;
        uint2 w;
        w.x = (unsigned int)f2bf(o[nt4][0]) | ((unsigned int)f2bf(o[nt4][1]) << 16);
        w.y = (unsigned int)f2bf(o[nt4][2]) | ((unsigned int)f2bf(o[nt4][3]) << 16);
        *(uint2*)op = w;
    }
}

// ---------------------------------------------------------------------------
extern "C" void kernel_launch(void* const* d_in, const int* in_sizes, int n_in,
                              void* d_out, int out_size, void* d_ws, size_t ws_size,
                              hipStream_t stream)
{
    const float* x      = (const float*)d_in[0];
    const float* cv1_w  = (const float*)d_in[1];
    const float* bn1_g  = (const float*)d_in[2];
    const float* bn1_b  = (const float*)d_in[3];
    const float* bn1_m  = (const float*)d_in[4];
    const float* bn1_v  = (const float*)d_in[5];
    const float* cv2_w  = (const float*)d_in[6];
    const float* bn2_g  = (const float*)d_in[7];
    const float* bn2_b  = (const float*)d_in[8];
    const float* bn2_m  = (const float*)d_in[9];
    const float* bn2_v  = (const float*)d_in[10];
    const float* ln1_g  = (const float*)d_in[11];
    const float* ln1_b  = (const float*)d_in[12];
    const float* qkv_w  = (const float*)d_in[13];
    const float* qkv_b  = (const float*)d_in[14];
    const float* proj_w = (const float*)d_in[15];
    const float* proj_b = (const float*)d_in[16];
    const float* gamma  = (const float*)d_in[17];
    const float* ln2_g  = (const float*)d_in[18];
    const float* ln2_b  = (const float*)d_in[19];
    const float* ffn_w1 = (const float*)d_in[20];
    const float* ffn_b1 = (const float*)d_in[21];
    const float* ffn_w2 = (const float*)d_in[22];
    const float* ffn_b2 = (const float*)d_in[23];

    ushort* W = (ushort*)d_ws;
    ushort* y    = W;                                  // N*256 bf16
    ushort* f    = y    + (size_t)NPOS * 256;          // N*128
    ushort* tmp  = f    + (size_t)NPOS * 128;          // N*128 (fn1 / oh / fn2)
    ushort* owb  = tmp  + (size_t)NPOS * 128;          // N*128 (out_w)
    ushort* qkvb = owb  + (size_t)NPOS * 128;          // N*384
    ushort* xT   = qkvb + (size_t)NPOS * 384;          // N*256 (UNUSED, kept for layout)
    ushort* wc1  = xT   + (size_t)NPOS * 256;          // 65536
    ushort* wqkv = wc1  + 65536;                       // 49152
    ushort* wpr  = wqkv + 49152;                       // 16384
    ushort* ww1  = wpr  + 16384;                       // 32768
    ushort* ww2  = ww1  + 32768;                       // 32768
    ushort* wc2  = ww2  + 32768;                       // 98304
    float*  bns1 = (float*)(wc2 + 98304);              // 256
    float*  bnb1 = bns1 + 256;
    float*  bns2 = bnb1 + 256;
    float*  bnb2 = bns2 + 256;
    float*  out  = (float*)d_out;

    WcvtArgs wa;
    wa.src[0] = cv1_w;  wa.dst[0] = wc1;  wa.n[0] = 65536;
    wa.src[1] = qkv_w;  wa.dst[1] = wqkv; wa.n[1] = 49152;
    wa.src[2] = proj_w; wa.dst[2] = wpr;  wa.n[2] = 16384;
    wa.src[3] = ffn_w1; wa.dst[3] = ww1;  wa.n[3] = 32768;
    wa.src[4] = ffn_w2; wa.dst[4] = ww2;  wa.n[4] = 32768;
    wa.src[5] = cv2_w;  wa.dst[5] = wc2;  wa.n[5] = 98304;
    wcvt_k<<<dim3(96, 6), 256, 0, stream>>>(wa);
    bnprep_k<<<2, 256, 0, stream>>>(bn1_g, bn1_b, bn1_m, bn1_v,
                                    bn2_g, bn2_b, bn2_m, bn2_v,
                                    bns1, bnb1, bns2, bnb2);

    // 1) cv1 + BN + SiLU -> y ; LN1(y2) -> tmp  (A staged from x NCHW, fused
    //    transpose: tr_k eliminated)
    gemm_k<256, 0, 4, 1, 1><<<dim3(1024, 2), 256, 0, stream>>>(
        (const ushort*)x, nullptr, wc1, nullptr, bns1, bnb1, nullptr, ln1_g, ln1_b,
        tmp, y, 256);
    // 2) qkv = fn1 @ qkv_w^T + b -> qkvb
    gemm_k<128, 128, 0, 0, 0><<<dim3(1024, 3), 256, 0, stream>>>(
        tmp, nullptr, wqkv, qkv_b, nullptr, nullptr, nullptr, nullptr, nullptr,
        nullptr, qkvb, 384);
    // 3) axial attention (both dirs) -> tmp (out_h), owb (out_w)
    attn_k<<<dim3(2048, 2), 256, 0, stream>>>(qkvb, tmp, owb);
    // 4) f = y2 + (avg(oh,ow) @ proj^T + b)*gamma ; LN2(f) -> tmp (fused)
    gemm_k<128, 128, 3, 4, 1><<<dim3(1024, 1), 256, 0, stream>>>(
        tmp, owb, wpr, proj_b, gamma, nullptr, y, ln2_g, ln2_b, tmp, f, 128);
    // 5) f += W2 @ gelu(W1 @ fn2 + b1) + b2  (fused FFN)
    ffn_k<<<1024, 256, 0, stream>>>(tmp, ww1, ffn_b1, ww2, ffn_b2, f);
    // 6) cv2(concat[y,f]) + BN + SiLU -> out NCHW fp32
    gemm_k<384, 0, 2, 2, 0><<<dim3(1024, 2), 256, 0, stream>>>(
        y, f, wc2, nullptr, bns2, bnb2, nullptr, nullptr, nullptr, nullptr, out, 0);
}

// Round 8
// 327.676 us; speedup vs baseline: 1.1727x; 1.1727x over previous
//
#include <hip/hip_runtime.h>
#include <math.h>

#define LEPS 1e-5f
static constexpr int NPOS = 65536;   // B*H*W = 16*64*64

typedef __attribute__((ext_vector_type(8))) short short8;
typedef __attribute__((ext_vector_type(4))) float floatx4;

__device__ __forceinline__ ushort f2bf(float f) {
    unsigned int u = __float_as_uint(f);
    u += 0x7FFF + ((u >> 16) & 1);          // RNE
    return (ushort)(u >> 16);
}
__device__ __forceinline__ float bfu(ushort h) {
    return __uint_as_float((unsigned int)h << 16);
}
__device__ __forceinline__ float bfl(unsigned int u) {
    return __uint_as_float(u << 16);
}
__device__ __forceinline__ float bfh(unsigned int u) {
    return __uint_as_float(u & 0xffff0000u);
}

// direct global -> LDS DMA, 16B per lane.  LDS dest = wave-uniform base + lane*16.
typedef __attribute__((address_space(1))) const unsigned int gu32_t;
typedef __attribute__((address_space(3))) unsigned int lu32_t;
__device__ __forceinline__ void gld16(const ushort* g, ushort* l) {
    __builtin_amdgcn_global_load_lds((gu32_t*)g, (lu32_t*)l, 16, 0, 0);
}

// ---------------------------------------------------------------------------
// Weight fp32 -> bf16, 6 segments (grid.y = segment)
// ---------------------------------------------------------------------------
struct WcvtArgs { const float* src[6]; ushort* dst[6]; int n[6]; };
__global__ __launch_bounds__(256)
void wcvt_k(WcvtArgs a)
{
    const int seg = blockIdx.y;
    const float* s = a.src[seg];
    ushort* d = a.dst[seg];
    const int n = a.n[seg];
    for (int i = blockIdx.x * 256 + threadIdx.x; i < n; i += gridDim.x * 256)
        d[i] = f2bf(s[i]);
}

// BN fold for both BNs in one launch (grid.x = which)
__global__ __launch_bounds__(256)
void bnprep_k(const float* g1, const float* b1, const float* m1, const float* v1,
              const float* g2, const float* b2, const float* m2, const float* v2,
              float* s1, float* h1, float* s2, float* h2)
{
    const int i = threadIdx.x;
    if (blockIdx.x == 0) {
        const float s = g1[i] * rsqrtf(v1[i] + LEPS);
        s1[i] = s; h1[i] = b1[i] - m1[i] * s;
    } else {
        const float s = g2[i] * rsqrtf(v2[i] + LEPS);
        s2[i] = s; h2[i] = b2[i] - m2[i] * s;
    }
}

// ---------------------------------------------------------------------------
// x NCHW fp32 -> xT [p][c] bf16  (p = b*4096 + hw)
// ---------------------------------------------------------------------------
__global__ __launch_bounds__(256)
void tr_k(const float* __restrict__ x, ushort* __restrict__ xT)
{
    __shared__ float tile[64][65];
    const int t = threadIdx.x;
    const int bi = blockIdx.x;          // 16 b * 4 ctile * 64 hwtile
    const int hwt = bi & 63, ct = (bi >> 6) & 3, b = bi >> 8;
    const int p0 = b * 4096 + hwt * 64, c0 = ct * 64;
    const float* src = x + ((size_t)(b * 256 + c0) << 12) + hwt * 64;
#pragma unroll
    for (int i = 0; i < 16; i++) {
        int cc = (t >> 6) + i * 4;
        tile[cc][t & 63] = src[((size_t)cc << 12) + (t & 63)];
    }
    __syncthreads();
    const int c2 = (t & 31) * 2;
    const int pr = t >> 5;
#pragma unroll
    for (int i = 0; i < 8; i++) {
        int pp = pr + i * 8;
        unsigned int u = (unsigned int)f2bf(tile[c2][pp])
                       | ((unsigned int)f2bf(tile[c2 + 1][pp]) << 16);
        *(unsigned int*)&xT[(size_t)(p0 + pp) * 256 + c0 + c2] = u;
    }
}

// ---------------------------------------------------------------------------
// MFMA bf16 GEMM, 64x128 tile, BK=64, double-buffered with counted vmcnt
// (2-phase).  LDS 48 KB -> 3 blocks/CU.  128-B rows, zero-conflict XOR
// chunk-swizzle.  Grid: (p-tiles, o-tiles) p-major.
// AMODE 0: A0 bf16, stride ARS.   AMODE 2: concat(A0 256-stride, A1 128).
// AMODE 3: avg(A0,A1) stride 128, reg-staged issue-early/write-late.
// EPI 0:+bias->bf16  1:BN+SiLU->bf16 (cv1)  2:BN+SiLU->fp32 NCHW (cv2)
// EPI 4: res(y2) + (v+bias)*gamma -> bf16 (proj)
// LN=1: additionally LayerNorm each 128-ch row of this tile -> lnout
// ---------------------------------------------------------------------------
template<int KDIM, int ARS, int AMODE, int EPI, int LN>
__global__ __launch_bounds__(256)
void gemm_k(const ushort* __restrict__ A0, const ushort* __restrict__ A1,
            const ushort* __restrict__ Wm, const float* __restrict__ bias,
            const float* __restrict__ q0, const float* __restrict__ q1,
            const ushort* __restrict__ resh,
            const float* __restrict__ lng, const float* __restrict__ lnb,
            ushort* __restrict__ lnout, void* __restrict__ outv, int ors)
{
    constexpr int NT = KDIM / 64;
    __shared__ __align__(16) ushort smem[24576];   // 48 KB
    const int t = threadIdx.x;
    const int p0 = blockIdx.x * 64;           // position tile (p-major adjacency)
    const int o0 = blockIdx.y * 128;          // output-channel tile
    const int lane = t & 63, wv = t >> 6;
    const int wn = wv * 32;                   // per-wave 64x32 output
    const int ln15 = lane & 15, quad = lane >> 4;
    const int dl_row = lane >> 3;
    const int dl_sch = (lane & 7) ^ dl_row;
    const int c_off0 = ((quad) ^ (ln15 & 7)) * 8;
    const int c_off1 = ((4 + quad) ^ (ln15 & 7)) * 8;
    floatx4 acc[4][2] = {};

    // AMODE 3 reg-staging state (64 rows x 64 cols, 32 B/thread)
    const int a3row = t >> 2, a3q = t & 3;
    uint4 ra[2], rb4[2];

    auto stageA = [&](int k0, int bc) {            // AMODE 0/2: 2 instr/wave
#pragma unroll
        for (int i = 0; i < 2; i++) {
            const int r0 = wv * 16 + i * 8;
            const int row = r0 + dl_row;
            const ushort* src;
            if (AMODE == 2) {
                if (k0 < 256) src = A0 + (size_t)(p0 + row) * 256 + k0 + dl_sch * 8;
                else          src = A1 + (size_t)(p0 + row) * 128 + (k0 - 256) + dl_sch * 8;
            } else {
                src = A0 + (size_t)(p0 + row) * ARS + k0 + dl_sch * 8;
            }
            gld16(src, &smem[bc * 4096 + r0 * 64]);
        }
    };
    auto stageB = [&](int k0, int bc) {            // 4 instr/wave
#pragma unroll
        for (int i = 0; i < 4; i++) {
            const int r0 = wv * 32 + i * 8;
            gld16(Wm + (size_t)(o0 + r0 + dl_row) * KDIM + k0 + dl_sch * 8,
                  &smem[8192 + bc * 8192 + r0 * 64]);
        }
    };
    auto loadA3 = [&](int k0) {
        const ushort* s1 = A0 + (size_t)(p0 + a3row) * 128 + k0 + a3q * 16;
        const ushort* s2 = A1 + (size_t)(p0 + a3row) * 128 + k0 + a3q * 16;
#pragma unroll
        for (int i = 0; i < 2; i++) { ra[i] = ((const uint4*)s1)[i]; rb4[i] = ((const uint4*)s2)[i]; }
    };
    auto writeA3 = [&](int bc) {
#pragma unroll
        for (int i = 0; i < 2; i++) {
            const unsigned int* ap = (const unsigned int*)&ra[i];
            const unsigned int* bp = (const unsigned int*)&rb4[i];
            uint4 w; unsigned int* wp = (unsigned int*)&w;
#pragma unroll
            for (int j = 0; j < 4; j++)
                wp[j] = (unsigned int)f2bf(0.5f * (bfl(ap[j]) + bfl(bp[j])))
                      | ((unsigned int)f2bf(0.5f * (bfh(ap[j]) + bfh(bp[j]))) << 16);
            const int pch = (a3q * 2 + i) ^ (a3row & 7);
            *(uint4*)&smem[bc * 4096 + a3row * 64 + pch * 8] = w;
        }
    };
    auto compute = [&](int bc) {
#pragma unroll
        for (int kh = 0; kh < 2; kh++) {
            const int co = kh ? c_off1 : c_off0;
            short8 a[4], b[2];
#pragma unroll
            for (int i = 0; i < 4; i++)
                a[i] = *(const short8*)&smem[bc * 4096 + (i * 16 + ln15) * 64 + co];
#pragma unroll
            for (int j = 0; j < 2; j++)
                b[j] = *(const short8*)&smem[8192 + bc * 8192 + (wn + j * 16 + ln15) * 64 + co];
#pragma unroll
            for (int i = 0; i < 4; i++)
#pragma unroll
                for (int j = 0; j < 2; j++)
                    acc[i][j] = __builtin_amdgcn_mfma_f32_16x16x32_bf16(
                        a[i], b[j], acc[i][j], 0, 0, 0);
        }
    };

    if (AMODE == 3) {
        loadA3(0);
        stageB(0, 0);
#pragma unroll
        for (int tt = 0; tt < NT; ++tt) {
            const int cur = tt & 1;
            writeA3(cur);                          // waits own A regs, ds_write
            if (tt + 1 < NT) {
                loadA3((tt + 1) * 64);             // issue-early for next tile
                stageB((tt + 1) * 64, cur ^ 1);
                asm volatile("s_waitcnt vmcnt(8) lgkmcnt(0)" ::: "memory");
            } else {
                asm volatile("s_waitcnt vmcnt(0) lgkmcnt(0)" ::: "memory");
            }
            __builtin_amdgcn_s_barrier();
            __builtin_amdgcn_sched_barrier(0);
            compute(cur);
            __builtin_amdgcn_sched_barrier(0);
            __builtin_amdgcn_s_barrier();
        }
    } else {
        stageA(0, 0); stageB(0, 0);
#pragma unroll
        for (int tt = 0; tt < NT; ++tt) {
            const int cur = tt & 1;
            if (tt + 1 < NT) {
                stageA((tt + 1) * 64, cur ^ 1);
                stageB((tt + 1) * 64, cur ^ 1);
                asm volatile("s_waitcnt vmcnt(6)" ::: "memory");
            } else {
                asm volatile("s_waitcnt vmcnt(0)" ::: "memory");
            }
            __builtin_amdgcn_s_barrier();
            __builtin_amdgcn_sched_barrier(0);
            compute(cur);
            __builtin_amdgcn_sched_barrier(0);
            __builtin_amdgcn_s_barrier();
        }
    }

    if (EPI == 2) {
        // BN+SiLU, coalesced NCHW fp32 store via LDS transpose (two 64-ch chunks)
        float* cb = (float*)smem;                       // [64][72] fp32 = 18.4 KB
        float* ob = (float*)outv + (((size_t)(p0 >> 12) * 256) << 12);
        const int hw0 = p0 & 4095;
#pragma unroll
        for (int chunk = 0; chunk < 2; chunk++) {
            __syncthreads();
            if ((wv >> 1) == chunk) {
#pragma unroll
                for (int i = 0; i < 4; i++)
#pragma unroll
                for (int j = 0; j < 2; j++) {
                    const int chl = (wv & 1) * 32 + j * 16 + ln15;
                    const int o = o0 + chunk * 64 + chl;
                    const float sc = q0[o], sh = q1[o];
#pragma unroll
                    for (int r = 0; r < 4; r++) {
                        const int pos = i * 16 + quad * 4 + r;
                        float v = acc[i][j][r] * sc + sh;
                        v = v / (1.f + __expf(-v));
                        cb[chl * 72 + pos] = v;
                    }
                }
            }
            __syncthreads();
#pragma unroll
            for (int it = 0; it < 4; it++) {
                const int flat = it * 256 + t;
                const int ch = flat >> 4, posq = (flat & 15) * 4;
                const int o = o0 + chunk * 64 + ch;
                float4 v4 = *(const float4*)&cb[ch * 72 + posq];
                *(float4*)&ob[((size_t)o << 12) + hw0 + posq] = v4;
            }
        }
        return;
    }

    // ---- EPI 0/1/4: epilogue through LDS tile (also feeds LN) ----
    const bool lnact = LN && (EPI != 1 || o0 == 128);
    ushort (*lt)[136] = (ushort (*)[136])smem;          // 64 x 136 = 17.4 KB
#pragma unroll
    for (int i = 0; i < 4; i++) {
#pragma unroll
        for (int r = 0; r < 4; r++) {
            const int lr = i * 16 + quad * 4 + r;       // 0..63
            const int p = p0 + lr;
#pragma unroll
            for (int j = 0; j < 2; j++) {
                const int ol = wn + j * 16 + ln15;
                const int o = o0 + ol;
                float v = acc[i][j][r];
                if (EPI == 0) {
                    v += bias[o];
                } else if (EPI == 1) {
                    v = v * q0[o] + q1[o];
                    v = v / (1.f + __expf(-v));
                } else if (EPI == 4) {
                    v = bfu(resh[(size_t)p * 256 + 128 + o]) + (v + bias[o]) * q0[o];
                }
                lt[lr][ol] = f2bf(v);
            }
        }
    }
    __syncthreads();
    // coalesced store: 64 rows x 256 B, 4 x uint4 per thread
    {
        ushort* o16 = (ushort*)outv;
#pragma unroll
        for (int it = 0; it < 4; it++) {
            const int flat = it * 256 + t;
            const int row = flat >> 4, ch = (flat & 15) * 8;
            *(uint4*)&o16[(size_t)(p0 + row) * (size_t)ors + o0 + ch] =
                *(const uint4*)&lt[row][ch];
        }
    }

    if (lnact && t < 128) {
        const int rrow = t >> 1, rhalf = t & 1;         // rrow 0..63
        const ushort* rp = &lt[rrow][rhalf * 64];
        float s = 0.f, s2 = 0.f;
#pragma unroll
        for (int i = 0; i < 8; i++) {
            const uint4 u = *(const uint4*)(rp + i * 8);
            const unsigned int ww[4] = {u.x, u.y, u.z, u.w};
#pragma unroll
            for (int j = 0; j < 4; j++) {
                const float a = bfl(ww[j]), c = bfh(ww[j]);
                s += a + c; s2 += a * a + c * c;
            }
        }
        s += __shfl_xor(s, 1); s2 += __shfl_xor(s2, 1);
        const float mu = s * (1.f / 128.f);
        const float rn = rsqrtf(s2 * (1.f / 128.f) - mu * mu + LEPS);
        ushort* op = lnout + (size_t)(p0 + rrow) * 128 + rhalf * 64;
#pragma unroll
        for (int i = 0; i < 8; i++) {
            const uint4 u = *(const uint4*)(rp + i * 8);
            const unsigned int ww[4] = {u.x, u.y, u.z, u.w};
            uint4 wout;
            unsigned int* wo = (unsigned int*)&wout;
#pragma unroll
            for (int j = 0; j < 4; j++) {
                const int ch = rhalf * 64 + i * 8 + j * 2;
                const float2 gg = *(const float2*)(lng + ch);
                const float2 bb = *(const float2*)(lnb + ch);
                const float a = (bfl(ww[j]) - mu) * rn * gg.x + bb.x;
                const float c = (bfh(ww[j]) - mu) * rn * gg.y + bb.y;
                wo[j] = (unsigned int)f2bf(a) | ((unsigned int)f2bf(c) << 16);
            }
            *(uint4*)(op + i * 8) = wout;
        }
    }
}

// ---------------------------------------------------------------------------
// Fused FFN: f += W2 @ gelu(W1 @ fn2 + b1) + b2.  64 positions/block.
// GEMM1: single-burst stage of full Ax[64][128] + W1[256][128] (20 gld16/wave,
// one vmcnt(0)+barrier), then 4 barrier-free K-steps.  GEMM2: w2 dbuf with
// counted vmcnt; w2 tile0 issued under the H1 epilogue; f-RMW tile prefetched
// into the dead w2 buffer at the last step.  LDS 80 KB (2 blocks/CU).
// ---------------------------------------------------------------------------
__global__ __launch_bounds__(256)
void ffn_k(const ushort* __restrict__ fn2, const ushort* __restrict__ w1,
           const float* __restrict__ b1, const ushort* __restrict__ w2,
           const float* __restrict__ b2, ushort* __restrict__ f)
{
    __shared__ __align__(16) ushort smem[40960];         // 80 KB
    // GEMM1: Ax [0,8192) = [64][128] swz ; W1 [8192,40960) = [256][128] swz
    // GEMM2: H1 [0,16896) = [64][264] ; w2 dbuf [16896,33280) = 2x[128][64] swz
    const int t = threadIdx.x;
    const int p0 = blockIdx.x * 64;
    const int lane = t & 63, wv = t >> 6;
    const int ln15 = lane & 15, quad = lane >> 4;
    // 64-col DMA map (w2, f): 8 rows/instr
    const int dl_row = lane >> 3;
    const int dl_sch = (lane & 7) ^ dl_row;
    // 128-col DMA map (Ax, W1): 4 rows/instr, 16 chunks, swz chunk^(row&7)
    const int dl4_row = lane >> 4;
    const int dl4_c   = lane & 15;
    // 64-col fragment offsets
    const int c_off0 = ((quad) ^ (ln15 & 7)) * 8;
    const int c_off1 = ((4 + quad) ^ (ln15 & 7)) * 8;

    float bb1[4], bb2[2];
#pragma unroll
    for (int j = 0; j < 4; j++) bb1[j] = b1[wv * 64 + j * 16 + ln15];
#pragma unroll
    for (int j = 0; j < 2; j++) bb2[j] = b2[wv * 32 + j * 16 + ln15];

    // ---- single-burst stage: Ax (4 instr/wave) + W1 (16 instr/wave) ----
#pragma unroll
    for (int i = 0; i < 4; i++) {
        const int r0 = wv * 16 + i * 4;
        const int row = r0 + dl4_row;
        const int sch = dl4_c ^ (row & 7);
        gld16(fn2 + (size_t)(p0 + row) * 128 + sch * 8, &smem[r0 * 128]);
    }
#pragma unroll
    for (int i = 0; i < 16; i++) {
        const int r0 = wv * 64 + i * 4;
        const int row = r0 + dl4_row;
        const int sch = dl4_c ^ (row & 7);
        gld16(w1 + (size_t)row * 128 + sch * 8, &smem[8192 + r0 * 128]);
    }
    asm volatile("s_waitcnt vmcnt(0)" ::: "memory");
    __builtin_amdgcn_s_barrier();
    __builtin_amdgcn_sched_barrier(0);

    // ---- GEMM1 compute: 4 K-steps, barrier-free (single-buffer read-only) ----
    floatx4 acc1[4][4] = {};
#pragma unroll
    for (int kk = 0; kk < 4; kk++) {
        const int co = ((kk * 4 + quad) ^ (ln15 & 7)) * 8;
        short8 a[4], b[4];
#pragma unroll
        for (int i = 0; i < 4; i++)
            a[i] = *(const short8*)&smem[(i * 16 + ln15) * 128 + co];
#pragma unroll
        for (int j = 0; j < 4; j++)
            b[j] = *(const short8*)&smem[8192 + (wv * 64 + j * 16 + ln15) * 128 + co];
#pragma unroll
        for (int i = 0; i < 4; i++)
#pragma unroll
            for (int j = 0; j < 4; j++)
                acc1[i][j] = __builtin_amdgcn_mfma_f32_16x16x32_bf16(
                    a[i], b[j], acc1[i][j], 0, 0, 0);
    }
    __builtin_amdgcn_s_barrier();                        // all Ax/W1 reads done
    __builtin_amdgcn_sched_barrier(0);

    // issue w2 tile0 DMA (overlaps H1 epilogue below); buf0 at 16896
#pragma unroll
    for (int i = 0; i < 4; i++) {
        const int r0 = wv * 32 + i * 8;
        gld16(w2 + (size_t)(r0 + dl_row) * 256 + dl_sch * 8,
              &smem[16896 + r0 * 64]);
    }
    // ---- H1 epilogue: gelu -> H1 [64][264] at 0 ----
    {
        ushort (*H1)[264] = (ushort (*)[264])smem;
#pragma unroll
        for (int i = 0; i < 4; i++)
#pragma unroll
        for (int j = 0; j < 4; j++)
#pragma unroll
        for (int r = 0; r < 4; r++) {
            float v = acc1[i][j][r] + bb1[j];
            v = 0.5f * v * (1.f + erff(v * 0.70710678118654752f));
            H1[i * 16 + quad * 4 + r][wv * 64 + j * 16 + ln15] = f2bf(v);
        }
    }
    asm volatile("s_waitcnt lgkmcnt(0)" ::: "memory");   // H1 visible; w2 DMA flies
    __builtin_amdgcn_s_barrier();
    __builtin_amdgcn_sched_barrier(0);

    // ---- GEMM2: fo[64][128] = h1 @ w2^T, w2 tiles double-buffered ----
    ushort (*H1)[264] = (ushort (*)[264])smem;
    floatx4 acc2[4][2] = {};
#pragma unroll
    for (int t4 = 0; t4 < 4; ++t4) {
        const int cur = t4 & 1;
        if (t4 + 1 < 4) {
#pragma unroll
            for (int i = 0; i < 4; i++) {
                const int r0 = wv * 32 + i * 8;
                gld16(w2 + (size_t)(r0 + dl_row) * 256 + (t4 + 1) * 64 + dl_sch * 8,
                      &smem[16896 + (cur ^ 1) * 8192 + r0 * 64]);
            }
            asm volatile("s_waitcnt vmcnt(4)" ::: "memory");
        } else {
            // prefetch f tile for the RMW into the dead w2 buf0 (16 KB exact)
#pragma unroll
            for (int i = 0; i < 4; i++) {
                const int r0 = wv * 16 + i * 4;
                gld16(f + (size_t)(p0 + r0 + (lane >> 4)) * 128 + (lane & 15) * 8,
                      &smem[16896 + (cur ^ 1) * 8192 + r0 * 128]);
            }
            asm volatile("s_waitcnt vmcnt(4)" ::: "memory");
        }
        __builtin_amdgcn_s_barrier();
        __builtin_amdgcn_sched_barrier(0);
#pragma unroll
        for (int kh = 0; kh < 2; kh++) {
            const int co = kh ? c_off1 : c_off0;
            short8 a[4], b[2];
#pragma unroll
            for (int i = 0; i < 4; i++)
                a[i] = *(const short8*)&H1[i * 16 + ln15][t4 * 64 + kh * 32 + quad * 8];
#pragma unroll
            for (int j = 0; j < 2; j++)
                b[j] = *(const short8*)&smem[16896 + cur * 8192
                                             + (wv * 32 + j * 16 + ln15) * 64 + co];
#pragma unroll
            for (int i = 0; i < 4; i++)
#pragma unroll
                for (int j = 0; j < 2; j++)
                    acc2[i][j] = __builtin_amdgcn_mfma_f32_16x16x32_bf16(
                        a[i], b[j], acc2[i][j], 0, 0, 0);
        }
        __builtin_amdgcn_sched_barrier(0);
        __builtin_amdgcn_s_barrier();
    }
    asm volatile("s_waitcnt vmcnt(0)" ::: "memory");     // all waves' f-DMA done
    __builtin_amdgcn_s_barrier();

    // ---- f RMW in LDS (buf0 region), then coalesced store back ----
    ushort* Ft = &smem[16896];                           // [64][128] linear
    {
#pragma unroll
        for (int i = 0; i < 4; i++)
#pragma unroll
        for (int r = 0; r < 4; r++) {
            const int pos = i * 16 + quad * 4 + r;
#pragma unroll
            for (int j = 0; j < 2; j++) {
                const int ch = wv * 32 + j * 16 + ln15;
                const int idx = pos * 128 + ch;
                Ft[idx] = f2bf(bfu(Ft[idx]) + acc2[i][j][r] + bb2[j]);
            }
        }
    }
    __syncthreads();
#pragma unroll
    for (int it = 0; it < 4; it++) {
        const int flat = it * 256 + t;
        const int row = flat >> 4, ch = (flat & 15) * 8;
        *(uint4*)&f[(size_t)(p0 + row) * 128 + ch] = *(const uint4*)&Ft[row * 128 + ch];
    }
}

// ---------------------------------------------------------------------------
// MFMA axial decay attention, both directions in one launch (blockIdx.y).
// ---------------------------------------------------------------------------
__global__ __launch_bounds__(256)
void attn_k(const ushort* __restrict__ qkv, ushort* __restrict__ oh,
            ushort* __restrict__ ow)
{
    __shared__ ushort VtS[4][16 * 72];    // V^T [d][j], stride 72
    __shared__ ushort SbS[4][64 * 72];    // S   [i][j], stride 72
    __shared__ float dpow[128];           // dpow[k] = e^{dec*|k-63|}
    const int t = threadIdx.x, wv = t >> 6, lane = t & 63;
    const int ln15 = lane & 15, quad = lane >> 4;
    const int dirH = (blockIdx.y == 0);
    ushort* outb = dirH ? oh : ow;
    const int blk = blockIdx.x;               // (b*8+n)*16 + lg
    const int lg = blk & 15, n = (blk >> 4) & 7, b = blk >> 7;
    if (t < 128) {
        const float dec = logf(1.f - exp2f(-2.f - 0.5f * (float)n));
        int d = t - 63; if (d < 0) d = -d;
        dpow[t] = __expf(dec * (float)d);
    }
    const int fixed = lg * 4 + wv;
    const int stride = dirH ? 64 : 1;
    const size_t base = (size_t)b * 4096 + (dirH ? fixed : fixed * 64);
    const size_t cbase = base * 384 + n * 16;

    // ---- stage V^T into LDS (lane = position j) ----
    {
        const ushort* vp = qkv + cbase + (size_t)lane * stride * 384 + 256;
        const uint4 va = *(const uint4*)vp, vb = *(const uint4*)(vp + 8);
        ushort* vt = VtS[wv] + lane;
        const unsigned int w[8] = { va.x, va.y, va.z, va.w, vb.x, vb.y, vb.z, vb.w };
#pragma unroll
        for (int d = 0; d < 8; d++) {
            vt[(2 * d) * 72]     = (ushort)(w[d] & 0xffff);
            vt[(2 * d + 1) * 72] = (ushort)(w[d] >> 16);
        }
    }
    // ---- load Q/K fragments (16x16x32, K dim padded 16->32) ----
    short8 qa[4], kb[4];
    {
        const short8 z = {0, 0, 0, 0, 0, 0, 0, 0};
#pragma unroll
        for (int mt = 0; mt < 4; mt++) {
            const int i = mt * 16 + ln15;
            if (quad < 2) {
                const ushort* qp = qkv + cbase + (size_t)i * stride * 384 + quad * 8;
                qa[mt] = *(const short8*)qp;
                kb[mt] = *(const short8*)(qp + 128);
            } else { qa[mt] = z; kb[mt] = z; }
        }
    }
    __syncthreads();

    // ---- QK^T + decay -> Sb (bf16 row-major) ----
#pragma unroll
    for (int mt = 0; mt < 4; mt++) {
#pragma unroll
        for (int nt = 0; nt < 4; nt++) {
            floatx4 c = {0.f, 0.f, 0.f, 0.f};
            c = __builtin_amdgcn_mfma_f32_16x16x32_bf16(qa[mt], kb[nt], c, 0, 0, 0);
            const int i0 = mt * 16 + quad * 4;
            const int jl = nt * 16 + ln15;
            const float* lut = dpow + (i0 - jl + 63);
            ushort* sb = SbS[wv] + i0 * 72 + jl;
#pragma unroll
            for (int r = 0; r < 4; r++)
                sb[r * 72] = f2bf(c[r] * lut[r]);
        }
    }
    __syncthreads();

    // ---- O^T = V^T * S^T  (M=16 d, N=64 i, K=64 j) ----
    short8 av[2];
#pragma unroll
    for (int c = 0; c < 2; c++)
        av[c] = *(const short8*)&VtS[wv][ln15 * 72 + c * 32 + quad * 8];
    floatx4 o[4] = {};
#pragma unroll
    for (int nt4 = 0; nt4 < 4; nt4++) {
#pragma unroll
        for (int c = 0; c < 2; c++) {
            const short8 bs = *(const short8*)
                &SbS[wv][(nt4 * 16 + ln15) * 72 + c * 32 + quad * 8];
            o[nt4] = __builtin_amdgcn_mfma_f32_16x16x32_bf16(av[c], bs, o[nt4], 0, 0, 0);
        }
    }
#pragma unroll
    for (int nt4 = 0; nt4 < 4; nt4++) {
        const int i = nt4 * 16 + ln15;
        ushort* op = outb + (base + (size_t)i * stride) * 128 + n * 16 + quad * 4;
        uint2 w;
        w.x = (unsigned int)f2bf(o[nt4][0]) | ((unsigned int)f2bf(o[nt4][1]) << 16);
        w.y = (unsigned int)f2bf(o[nt4][2]) | ((unsigned int)f2bf(o[nt4][3]) << 16);
        *(uint2*)op = w;
    }
}

// ---------------------------------------------------------------------------
extern "C" void kernel_launch(void* const* d_in, const int* in_sizes, int n_in,
                              void* d_out, int out_size, void* d_ws, size_t ws_size,
                              hipStream_t stream)
{
    const float* x      = (const float*)d_in[0];
    const float* cv1_w  = (const float*)d_in[1];
    const float* bn1_g  = (const float*)d_in[2];
    const float* bn1_b  = (const float*)d_in[3];
    const float* bn1_m  = (const float*)d_in[4];
    const float* bn1_v  = (const float*)d_in[5];
    const float* cv2_w  = (const float*)d_in[6];
    const float* bn2_g  = (const float*)d_in[7];
    const float* bn2_b  = (const float*)d_in[8];
    const float* bn2_m  = (const float*)d_in[9];
    const float* bn2_v  = (const float*)d_in[10];
    const float* ln1_g  = (const float*)d_in[11];
    const float* ln1_b  = (const float*)d_in[12];
    const float* qkv_w  = (const float*)d_in[13];
    const float* qkv_b  = (const float*)d_in[14];
    const float* proj_w = (const float*)d_in[15];
    const float* proj_b = (const float*)d_in[16];
    const float* gamma  = (const float*)d_in[17];
    const float* ln2_g  = (const float*)d_in[18];
    const float* ln2_b  = (const float*)d_in[19];
    const float* ffn_w1 = (const float*)d_in[20];
    const float* ffn_b1 = (const float*)d_in[21];
    const float* ffn_w2 = (const float*)d_in[22];
    const float* ffn_b2 = (const float*)d_in[23];

    ushort* W = (ushort*)d_ws;
    ushort* y    = W;                                  // N*256 bf16
    ushort* f    = y    + (size_t)NPOS * 256;          // N*128
    ushort* tmp  = f    + (size_t)NPOS * 128;          // N*128 (fn1 / oh / fn2)
    ushort* owb  = tmp  + (size_t)NPOS * 128;          // N*128 (out_w)
    ushort* qkvb = owb  + (size_t)NPOS * 128;          // N*384
    ushort* xT   = qkvb + (size_t)NPOS * 384;          // N*256
    ushort* wc1  = xT   + (size_t)NPOS * 256;          // 65536
    ushort* wqkv = wc1  + 65536;                       // 49152
    ushort* wpr  = wqkv + 49152;                       // 16384
    ushort* ww1  = wpr  + 16384;                       // 32768
    ushort* ww2  = ww1  + 32768;                       // 32768
    ushort* wc2  = ww2  + 32768;                       // 98304
    float*  bns1 = (float*)(wc2 + 98304);              // 256
    float*  bnb1 = bns1 + 256;
    float*  bns2 = bnb1 + 256;
    float*  bnb2 = bns2 + 256;
    float*  out  = (float*)d_out;

    WcvtArgs wa;
    wa.src[0] = cv1_w;  wa.dst[0] = wc1;  wa.n[0] = 65536;
    wa.src[1] = qkv_w;  wa.dst[1] = wqkv; wa.n[1] = 49152;
    wa.src[2] = proj_w; wa.dst[2] = wpr;  wa.n[2] = 16384;
    wa.src[3] = ffn_w1; wa.dst[3] = ww1;  wa.n[3] = 32768;
    wa.src[4] = ffn_w2; wa.dst[4] = ww2;  wa.n[4] = 32768;
    wa.src[5] = cv2_w;  wa.dst[5] = wc2;  wa.n[5] = 98304;
    wcvt_k<<<dim3(96, 6), 256, 0, stream>>>(wa);
    bnprep_k<<<2, 256, 0, stream>>>(bn1_g, bn1_b, bn1_m, bn1_v,
                                    bn2_g, bn2_b, bn2_m, bn2_v,
                                    bns1, bnb1, bns2, bnb2);
    tr_k<<<4096, 256, 0, stream>>>(x, xT);

    // 1) cv1 + BN + SiLU -> y ; LN1(y2) -> tmp (fused, o-tile 1 only)
    gemm_k<256, 256, 0, 1, 1><<<dim3(1024, 2), 256, 0, stream>>>(
        xT, nullptr, wc1, nullptr, bns1, bnb1, nullptr, ln1_g, ln1_b, tmp, y, 256);
    // 2) qkv = fn1 @ qkv_w^T + b -> qkvb
    gemm_k<128, 128, 0, 0, 0><<<dim3(1024, 3), 256, 0, stream>>>(
        tmp, nullptr, wqkv, qkv_b, nullptr, nullptr, nullptr, nullptr, nullptr,
        nullptr, qkvb, 384);
    // 3) axial attention (both dirs) -> tmp (out_h), owb (out_w)
    attn_k<<<dim3(2048, 2), 256, 0, stream>>>(qkvb, tmp, owb);
    // 4) f = y2 + (avg(oh,ow) @ proj^T + b)*gamma ; LN2(f) -> tmp (fused)
    gemm_k<128, 128, 3, 4, 1><<<dim3(1024, 1), 256, 0, stream>>>(
        tmp, owb, wpr, proj_b, gamma, nullptr, y, ln2_g, ln2_b, tmp, f, 128);
    // 5) f += W2 @ gelu(W1 @ fn2 + b1) + b2  (fused FFN)
    ffn_k<<<1024, 256, 0, stream>>>(tmp, ww1, ffn_b1, ww2, ffn_b2, f);
    // 6) cv2(concat[y,f]) + BN + SiLU -> out NCHW fp32
    gemm_k<384, 0, 2, 2, 0><<<dim3(1024, 2), 256, 0, stream>>>(
        y, f, wc2, nullptr, bns2, bnb2, nullptr, nullptr, nullptr, nullptr, out, 0);
}